// Round 5
// baseline (598.368 us; speedup 1.0000x reference)
//
#include <hip/hip_runtime.h>

using bf8 = __attribute__((ext_vector_type(8))) short;   // 8 bf16 (4 VGPRs) — MFMA A/B frag
using bf4 = __attribute__((ext_vector_type(4))) short;
using f4  = __attribute__((ext_vector_type(4))) float;   // MFMA C/D frag
using u16 = unsigned short;

#define NROWS 262144

// workspace byte layout (all 128B-aligned)
#define FLAG_B   0                       // int: 0 = bf16 inputs, 1 = fp32 inputs
#define PU_B     128                     // packed [U1;U2] B-frags (K=256,N=128): 32768 u16
#define PV_B     (PU_B + 65536)          // packed V = [U1;U2]@[Whrz|Whn] (K=256,N=384): 98304 u16
#define PWI_B    (PV_B + 196608)         // packed Wi padded to K=32 (row4 = bi): 12288 u16
#define BHN_B    (PWI_B + 24576)         // bhn as f32: 128
// total ~287 KB

#define N_PU   32768
#define N_PV   98304
#define N_PWI  12288
#define PACK_ITEMS (N_PU + N_PV + N_PWI + 128)

static __device__ __forceinline__ float bf2f(u16 u) {
    unsigned v = ((unsigned)u) << 16;
    return __builtin_bit_cast(float, v);
}
static __device__ __forceinline__ u16 f2bf(float f) {
    unsigned x = __builtin_bit_cast(unsigned, f);
    x = x + 0x7fffu + ((x >> 16) & 1u);          // RNE (inputs are finite)
    return (u16)(x >> 16);
}

// ---- dtype-dispatch helpers: FP32 => buffers hold float, else bf16 ----
template<bool FP32>
static __device__ __forceinline__ u16 ldw(const void* p, int i) {   // -> bf16 bits
    if constexpr (FP32) return f2bf(((const float*)p)[i]);
    else                return ((const u16*)p)[i];
}
template<bool FP32>
static __device__ __forceinline__ float ldf(const void* p, int i) { // -> float
    if constexpr (FP32) return ((const float*)p)[i];
    else                return bf2f(((const u16*)p)[i]);
}
template<bool FP32>
static __device__ __forceinline__ bf8 ld8(const void* base, int idx) { // 8 contiguous
    if constexpr (!FP32) {
        return *(const bf8*)((const u16*)base + idx);
    } else {
        const float* f = (const float*)base + idx;
        f4 u = *(const f4*)f;
        f4 v = *(const f4*)(f + 4);
        bf8 r;
        r[0]=(short)f2bf(u[0]); r[1]=(short)f2bf(u[1]); r[2]=(short)f2bf(u[2]); r[3]=(short)f2bf(u[3]);
        r[4]=(short)f2bf(v[0]); r[5]=(short)f2bf(v[1]); r[6]=(short)f2bf(v[2]); r[7]=(short)f2bf(v[3]);
        return r;
    }
}

// ---- mode detection: even-index u16s of real bf16 N(0,1) data never have
// exponent >= 0xC0 (|v| >= 2^65); fp32 data read as bf16 hits it ~25%/sample.
__global__ void detect_mode(const u16* __restrict__ h1u, int* __restrict__ flag) {
    if (threadIdx.x == 0 && blockIdx.x == 0) {
        int huge = 0;
#pragma unroll 8
        for (int i = 0; i < 256; ++i) {
            u16 v = h1u[i * 2];
            huge += (((v >> 7) & 0xFF) >= 0xC0);
        }
        *flag = (huge > 0) ? 1 : 0;
    }
}

// ---- pack weights into B-fragment order for mfma_f32_16x16x32_bf16:
// frag (nt,kb): lane l holds W[k = kb*32 + (l>>4)*8 + j][n = nt*16 + (l&15)], j=0..7
// pV holds the COMBINED weights V[k][n] = sum_j2 [U1;U2][k][j2] * [Whrz|Whn][j2][n],
// computed on the fly in fp32 (12.6 MFLOP total, all operands L2-resident).
// pWi holds Wi zero-padded to K=32 with row k=4 = bi (the x A-frag carries 1.0 at k=4).
template<bool FP32>
__global__ void prep_pack(const void* __restrict__ U1, const void* __restrict__ U2,
                          const void* __restrict__ Whrz, const void* __restrict__ Whn,
                          const void* __restrict__ Wi, const void* __restrict__ bi,
                          const void* __restrict__ bhn, char* __restrict__ ws,
                          const int* __restrict__ flag)
{
    if ((*flag != 0) != FP32) return;
    int e = blockIdx.x * 256 + threadIdx.x;
    if (e >= PACK_ITEMS) return;
    u16*   pU   = (u16*)(ws + PU_B);
    u16*   pV   = (u16*)(ws + PV_B);
    u16*   pWi  = (u16*)(ws + PWI_B);
    float* bhnF = (float*)(ws + BHN_B);
    if (e < N_PU) {                          // [U1;U2]: K=256 (KB=8), N=128 (NT=8)
        int j = e & 7, lane = (e >> 3) & 63, f = e >> 9;
        int kb = f & 7, nt = f >> 3;
        int k = kb * 32 + (lane >> 4) * 8 + j;
        int n = nt * 16 + (lane & 15);
        pU[e] = (k < 128) ? ldw<FP32>(U1, k * 128 + n) : ldw<FP32>(U2, (k - 128) * 128 + n);
    } else if (e < N_PU + N_PV) {            // V: K=256 (KB=8), N=384 (NT=24)
        int e2 = e - N_PU;
        int j = e2 & 7, lane = (e2 >> 3) & 63, f = e2 >> 9;
        int kb = f & 7, nt = f >> 3;
        int k = kb * 32 + (lane >> 4) * 8 + j;
        int n = nt * 16 + (lane & 15);
        const void* Us = (k < 128) ? U1 : U2;
        int krow = (k < 128) ? k : k - 128;
        float acc = 0.f;
        if (n < 256) {
#pragma unroll 8
            for (int j2 = 0; j2 < 128; ++j2)
                acc = fmaf(ldf<FP32>(Us, krow * 128 + j2), ldf<FP32>(Whrz, j2 * 256 + n), acc);
        } else {
#pragma unroll 8
            for (int j2 = 0; j2 < 128; ++j2)
                acc = fmaf(ldf<FP32>(Us, krow * 128 + j2), ldf<FP32>(Whn, j2 * 128 + (n - 256)), acc);
        }
        pV[e2] = f2bf(acc);
    } else if (e < N_PU + N_PV + N_PWI) {    // Wi padded: K=32 (KB=1), N=384 (NT=24)
        int e3 = e - (N_PU + N_PV);
        int j = e3 & 7, lane = (e3 >> 3) & 63, nt = e3 >> 9;
        int k = (lane >> 4) * 8 + j;
        int n = nt * 16 + (lane & 15);
        u16 v = 0;
        if (k < 4)       v = ldw<FP32>(Wi, k * 384 + n);
        else if (k == 4) v = ldw<FP32>(bi, n);
        pWi[e3] = v;
    } else {
        int i = e - (N_PU + N_PV + N_PWI);
        bhnF[i] = ldf<FP32>(bhn, i);
    }
}

// ---- fused kernel: combined-weight formulation, zero LDS, zero barriers.
// h@W == h1@(U1@W) + h2@(U2@W), so ALL four hidden GEMMs (h, hr, hz, hn) run
// directly off the h1/h2 A-frags with K=256; i_proj (+bias) is an MFMA with a
// K=32 padded x-frag. h stays fp32 in registers for the blend and the output.
template<bool FP32>
__global__ __launch_bounds__(256, 3) void gru_fused(
    const void* __restrict__ xin, const void* __restrict__ h1,
    const void* __restrict__ h2, const char* __restrict__ ws,
    void* __restrict__ out, const int* __restrict__ flag, int write2)
{
    if ((*flag != 0) != FP32) return;
    const int tid = threadIdx.x;
    const int w  = tid >> 6;
    const int l  = tid & 63;
    const int q  = l >> 4;        // quad index
    const int lr = l & 15;        // A-frag row / C-frag col
    const int g0 = blockIdx.x * 128 + w * 32;

    const bf8* __restrict__ pU  = (const bf8*)(ws + PU_B);
    const bf8* __restrict__ pV  = (const bf8*)(ws + PV_B);
    const bf8* __restrict__ pWi = (const bf8*)(ws + PWI_B);
    const float* __restrict__ bhnF = (const float*)(ws + BHN_B);

    // A-frags: lane holds A[row = lr][k = kb*32 + q*8 + j], contiguous in memory
    bf8 a[2][8];
#pragma unroll
    for (int m = 0; m < 2; ++m) {
        int row = g0 + m * 16 + lr;
        int base = row * 128 + q * 8;
#pragma unroll
        for (int kb = 0; kb < 4; ++kb) {
            a[m][kb]     = ld8<FP32>(h1, base + kb * 32);   // k in [0,128)   -> U1 part
            a[m][kb + 4] = ld8<FP32>(h2, base + kb * 32);   // k in [128,256) -> U2 part
        }
    }

    // x A-frag, K=32 padded: k=0..3 = x row, k=4 = 1.0 (bias row), rest 0
    bf8 ax[2];
#pragma unroll
    for (int m = 0; m < 2; ++m) {
        bf8 v = {0,0,0,0,0,0,0,0};
        if (q == 0) {
            int row = g0 + m * 16 + lr;
            if constexpr (FP32) {
                f4 xv = *(const f4*)((const float*)xin + row * 4);
#pragma unroll
                for (int k = 0; k < 4; ++k) v[k] = (short)f2bf(xv[k]);
            } else {
                bf4 xv = *(const bf4*)((const u16*)xin + row * 4);
#pragma unroll
                for (int k = 0; k < 4; ++k) v[k] = xv[k];
            }
            v[4] = (short)0x3F80;   // bf16 1.0
        }
        ax[m] = v;
    }

    float* outF = (float*)out;
    u16*   outB = (u16*)out;

#pragma unroll 1
    for (int nt = 0; nt < 8; ++nt) {
        const f4 z4 = {0.f, 0.f, 0.f, 0.f};
        f4 aH[2], aR[2], aZ[2], aN[2], aI[2];
        bf8 biR = pWi[(nt     ) * 64 + l];
        bf8 biZ = pWi[(nt + 8 ) * 64 + l];
        bf8 biN = pWi[(nt + 16) * 64 + l];
#pragma unroll
        for (int m = 0; m < 2; ++m) {
            aH[m] = z4;
            aN[m] = z4;                                            // FIX: was uninitialized (absmax 1.96 < 2 == tanh-bound signature)
            aR[m] = __builtin_amdgcn_mfma_f32_16x16x32_bf16(ax[m], biR, z4, 0, 0, 0);
            aZ[m] = __builtin_amdgcn_mfma_f32_16x16x32_bf16(ax[m], biZ, z4, 0, 0, 0);
            aI[m] = __builtin_amdgcn_mfma_f32_16x16x32_bf16(ax[m], biN, z4, 0, 0, 0);
        }
#pragma unroll
        for (int kb = 0; kb < 8; ++kb) {
            bf8 bH = pU[(nt * 8 + kb) * 64 + l];
            bf8 bR = pV[((nt     ) * 8 + kb) * 64 + l];   // V cols [0,128)   (hr)
            bf8 bZ = pV[((nt + 8 ) * 8 + kb) * 64 + l];   // V cols [128,256) (hz)
            bf8 bN = pV[((nt + 16) * 8 + kb) * 64 + l];   // V cols [256,384) (hn)
#pragma unroll
            for (int m = 0; m < 2; ++m) {
                aH[m] = __builtin_amdgcn_mfma_f32_16x16x32_bf16(a[m][kb], bH, aH[m], 0, 0, 0);
                aR[m] = __builtin_amdgcn_mfma_f32_16x16x32_bf16(a[m][kb], bR, aR[m], 0, 0, 0);
                aZ[m] = __builtin_amdgcn_mfma_f32_16x16x32_bf16(a[m][kb], bZ, aZ[m], 0, 0, 0);
                aN[m] = __builtin_amdgcn_mfma_f32_16x16x32_bf16(a[m][kb], bN, aN[m], 0, 0, 0);
            }
        }
        // C/D layout: col = lane&15, row = q*4 + reg  [m89-verified]
        int c = nt * 16 + lr;
        float bhc = bhnF[c];
#pragma unroll
        for (int m = 0; m < 2; ++m) {
            int rbase = (g0 + m * 16 + q * 4) * 128 + c;
#pragma unroll
            for (int i = 0; i < 4; ++i) {
                float hv = aH[m][i];                              // h in fp32, no round trip
                float sr = fminf(fmaxf(aR[m][i], -30.f), 30.f);   // = ir + bi_r + hr
                float r  = __fdividef(1.f, 1.f + __expf(-sr));
                float sz = fminf(fmaxf(aZ[m][i], -30.f), 30.f);
                float z  = __fdividef(1.f, 1.f + __expf(-sz));
                float t  = aI[m][i] + r * (aN[m][i] + bhc);       // i_n + bi_n + r*(hn + bhn)
                t = fminf(fmaxf(t, -15.f), 15.f);
                float e2t = __expf(2.f * t);
                float n = (e2t - 1.f) * __fdividef(1.f, e2t + 1.f);
                float o = (1.f - z) * n + z * hv;
                int off = rbase + i * 128;
                if constexpr (FP32) {
                    __builtin_nontemporal_store(o, outF + off);
                    if (write2) __builtin_nontemporal_store(o, outF + NROWS * 128 + off);
                } else {
                    u16 ob = f2bf(o);
                    __builtin_nontemporal_store(ob, outB + off);
                    if (write2) __builtin_nontemporal_store(ob, outB + NROWS * 128 + off);
                }
            }
        }
    }
}

extern "C" void kernel_launch(void* const* d_in, const int* in_sizes, int n_in,
                              void* d_out, int out_size, void* d_ws, size_t ws_size,
                              hipStream_t stream) {
    const void* x    = d_in[0];
    const void* h1   = d_in[1];
    const void* h2   = d_in[2];
    const void* U1   = d_in[3];
    const void* U2   = d_in[4];
    const void* Wi   = d_in[5];
    const void* bi   = d_in[6];
    const void* Whrz = d_in[7];
    const void* Whn  = d_in[8];
    const void* bhn  = d_in[9];
    char* ws   = (char*)d_ws;
    int* flag  = (int*)(ws + FLAG_B);
    int write2 = (out_size >= 2 * NROWS * 128) ? 1 : 0;

    detect_mode<<<1, 64, 0, stream>>>((const u16*)h1, flag);
    const int pblk = (PACK_ITEMS + 255) / 256;
    prep_pack<false><<<pblk, 256, 0, stream>>>(U1, U2, Whrz, Whn, Wi, bi, bhn, ws, flag);
    prep_pack<true ><<<pblk, 256, 0, stream>>>(U1, U2, Whrz, Whn, Wi, bi, bhn, ws, flag);
    gru_fused<false><<<NROWS / 128, 256, 0, stream>>>(x, h1, h2, ws, d_out, flag, write2);
    gru_fused<true ><<<NROWS / 128, 256, 0, stream>>>(x, h1, h2, ws, d_out, flag, write2);
}

// Round 6
// 586.843 us; speedup vs baseline: 1.0196x; 1.0196x over previous
//
#include <hip/hip_runtime.h>

using bf8 = __attribute__((ext_vector_type(8))) short;   // 8 bf16 (4 VGPRs) — MFMA A/B frag
using bf4 = __attribute__((ext_vector_type(4))) short;
using f4  = __attribute__((ext_vector_type(4))) float;   // MFMA C/D frag
using u16 = unsigned short;
using u64 = unsigned long long;

#define NROWS 262144

// workspace byte layout (all 128B-aligned)
#define FLAG_B   0                       // int: 0 = bf16 inputs, 1 = fp32 inputs
#define PU_B     128                     // packed [U1;U2] frags (K=256,N=128): 32768 u16
#define PV_B     (PU_B + 65536)          // packed V = [U1;U2]@[Whrz|Whn] (K=256,N=384): 98304 u16
#define PWI_B    (PV_B + 196608)         // packed Wi padded to K=32 (row4 = bi): 12288 u16
#define BHN_B    (PWI_B + 24576)         // bhn as f32: 128
// total ~287 KB

#define N_PU   32768
#define N_PV   98304
#define N_PWI  12288
#define PACK_ITEMS (N_PU + N_PV + N_PWI + 128)

static __device__ __forceinline__ float bf2f(u16 u) {
    unsigned v = ((unsigned)u) << 16;
    return __builtin_bit_cast(float, v);
}
static __device__ __forceinline__ u16 f2bf(float f) {
    unsigned x = __builtin_bit_cast(unsigned, f);
    x = x + 0x7fffu + ((x >> 16) & 1u);          // RNE (inputs are finite)
    return (u16)(x >> 16);
}

// ---- dtype-dispatch helpers: FP32 => buffers hold float, else bf16 ----
template<bool FP32>
static __device__ __forceinline__ u16 ldw(const void* p, int i) {   // -> bf16 bits
    if constexpr (FP32) return f2bf(((const float*)p)[i]);
    else                return ((const u16*)p)[i];
}
template<bool FP32>
static __device__ __forceinline__ float ldf(const void* p, int i) { // -> float
    if constexpr (FP32) return ((const float*)p)[i];
    else                return bf2f(((const u16*)p)[i]);
}
template<bool FP32>
static __device__ __forceinline__ bf8 ld8(const void* base, int idx) { // 8 contiguous
    if constexpr (!FP32) {
        return *(const bf8*)((const u16*)base + idx);
    } else {
        const float* f = (const float*)base + idx;
        f4 u = *(const f4*)f;
        f4 v = *(const f4*)(f + 4);
        bf8 r;
        r[0]=(short)f2bf(u[0]); r[1]=(short)f2bf(u[1]); r[2]=(short)f2bf(u[2]); r[3]=(short)f2bf(u[3]);
        r[4]=(short)f2bf(v[0]); r[5]=(short)f2bf(v[1]); r[6]=(short)f2bf(v[2]); r[7]=(short)f2bf(v[3]);
        return r;
    }
}

// ---- mode detection: even-index u16s of real bf16 N(0,1) data never have
// exponent >= 0xC0 (|v| >= 2^65); fp32 data read as bf16 hits it ~25%/sample.
__global__ void detect_mode(const u16* __restrict__ h1u, int* __restrict__ flag) {
    if (threadIdx.x == 0 && blockIdx.x == 0) {
        int huge = 0;
#pragma unroll 8
        for (int i = 0; i < 256; ++i) {
            u16 v = h1u[i * 2];
            huge += (((v >> 7) & 0xFF) >= 0xC0);
        }
        *flag = (huge > 0) ? 1 : 0;
    }
}

// ---- pack weights into MFMA fragment order for mfma_f32_16x16x32_bf16:
// frag (nt,kb): lane l holds W[k = kb*32 + (l>>4)*8 + j][n = nt*16 + (l&15)], j=0..7
// (this layout serves as EITHER operand; we use it as the A-operand so the
//  C/D "col = lane&15" slot carries the batch row -> lane-contiguous output)
// pV holds the COMBINED weights V[k][n] = sum_j2 [U1;U2][k][j2] * [Whrz|Whn][j2][n].
// pWi holds Wi zero-padded to K=32 with row k=4 = bi (x-frag carries 1.0 at k=4).
template<bool FP32>
__global__ void prep_pack(const void* __restrict__ U1, const void* __restrict__ U2,
                          const void* __restrict__ Whrz, const void* __restrict__ Whn,
                          const void* __restrict__ Wi, const void* __restrict__ bi,
                          const void* __restrict__ bhn, char* __restrict__ ws,
                          const int* __restrict__ flag)
{
    if ((*flag != 0) != FP32) return;
    int e = blockIdx.x * 256 + threadIdx.x;
    if (e >= PACK_ITEMS) return;
    u16*   pU   = (u16*)(ws + PU_B);
    u16*   pV   = (u16*)(ws + PV_B);
    u16*   pWi  = (u16*)(ws + PWI_B);
    float* bhnF = (float*)(ws + BHN_B);
    if (e < N_PU) {                          // [U1;U2]: K=256 (KB=8), N=128 (NT=8)
        int j = e & 7, lane = (e >> 3) & 63, f = e >> 9;
        int kb = f & 7, nt = f >> 3;
        int k = kb * 32 + (lane >> 4) * 8 + j;
        int n = nt * 16 + (lane & 15);
        pU[e] = (k < 128) ? ldw<FP32>(U1, k * 128 + n) : ldw<FP32>(U2, (k - 128) * 128 + n);
    } else if (e < N_PU + N_PV) {            // V: K=256 (KB=8), N=384 (NT=24)
        int e2 = e - N_PU;
        int j = e2 & 7, lane = (e2 >> 3) & 63, f = e2 >> 9;
        int kb = f & 7, nt = f >> 3;
        int k = kb * 32 + (lane >> 4) * 8 + j;
        int n = nt * 16 + (lane & 15);
        const void* Us = (k < 128) ? U1 : U2;
        int krow = (k < 128) ? k : k - 128;
        float acc = 0.f;
        if (n < 256) {
#pragma unroll 8
            for (int j2 = 0; j2 < 128; ++j2)
                acc = fmaf(ldf<FP32>(Us, krow * 128 + j2), ldf<FP32>(Whrz, j2 * 256 + n), acc);
        } else {
#pragma unroll 8
            for (int j2 = 0; j2 < 128; ++j2)
                acc = fmaf(ldf<FP32>(Us, krow * 128 + j2), ldf<FP32>(Whn, j2 * 128 + (n - 256)), acc);
        }
        pV[e2] = f2bf(acc);
    } else if (e < N_PU + N_PV + N_PWI) {    // Wi padded: K=32 (KB=1), N=384 (NT=24)
        int e3 = e - (N_PU + N_PV);
        int j = e3 & 7, lane = (e3 >> 3) & 63, nt = e3 >> 9;
        int k = (lane >> 4) * 8 + j;
        int n = nt * 16 + (lane & 15);
        u16 v = 0;
        if (k < 4)       v = ldw<FP32>(Wi, k * 384 + n);
        else if (k == 4) v = ldw<FP32>(bi, n);
        pWi[e3] = v;
    } else {
        int i = e - (N_PU + N_PV + N_PWI);
        bhnF[i] = ldf<FP32>(bhn, i);
    }
}

// ---- fused kernel: combined-weight formulation, zero LDS, zero barriers,
// SWAPPED MFMA operands: D = mfma(W_frag, h_frag) gives D[n][batch], so the
// C/D layout (col=lane&15, row=q*4+i) puts batch row in the lane slot and
// 4 CONSECUTIVE n-values in the 4 accumulator regs -> 16B-contiguous output
// per lane -> dwordx4 stores (round-5 counters showed the scalar C-layout
// stores cost +47MB WRITE / +27MB FETCH RMW amplification and 4x VMEM instrs).
template<bool FP32>
__global__ __launch_bounds__(256, 3) void gru_fused(
    const void* __restrict__ xin, const void* __restrict__ h1,
    const void* __restrict__ h2, const char* __restrict__ ws,
    void* __restrict__ out, const int* __restrict__ flag, int write2)
{
    if ((*flag != 0) != FP32) return;
    const int tid = threadIdx.x;
    const int w  = tid >> 6;
    const int l  = tid & 63;
    const int q  = l >> 4;        // quad index
    const int lr = l & 15;        // batch row within 16-tile (both as B-frag col and C col)
    const int g0 = blockIdx.x * 128 + w * 32;

    const bf8* __restrict__ pU  = (const bf8*)(ws + PU_B);
    const bf8* __restrict__ pV  = (const bf8*)(ws + PV_B);
    const bf8* __restrict__ pWi = (const bf8*)(ws + PWI_B);
    const float* __restrict__ bhnF = (const float*)(ws + BHN_B);

    // h-frags: lane holds h[batch = g0+m*16+lr][k = kb*32 + q*8 + j], contiguous.
    // (identical bytes serve as B-operand: B[k][col=lr] = h[batch=lr][k])
    bf8 a[2][8];
#pragma unroll
    for (int m = 0; m < 2; ++m) {
        int row = g0 + m * 16 + lr;
        int base = row * 128 + q * 8;
#pragma unroll
        for (int kb = 0; kb < 4; ++kb) {
            a[m][kb]     = ld8<FP32>(h1, base + kb * 32);   // k in [0,128)   -> U1 part
            a[m][kb + 4] = ld8<FP32>(h2, base + kb * 32);   // k in [128,256) -> U2 part
        }
    }

    // x B-frag, K=32 padded: k=0..3 = x row, k=4 = 1.0 (bias row), rest 0
    bf8 ax[2];
#pragma unroll
    for (int m = 0; m < 2; ++m) {
        bf8 v = {0,0,0,0,0,0,0,0};
        if (q == 0) {
            int row = g0 + m * 16 + lr;
            if constexpr (FP32) {
                f4 xv = *(const f4*)((const float*)xin + row * 4);
#pragma unroll
                for (int k = 0; k < 4; ++k) v[k] = (short)f2bf(xv[k]);
            } else {
                bf4 xv = *(const bf4*)((const u16*)xin + row * 4);
#pragma unroll
                for (int k = 0; k < 4; ++k) v[k] = xv[k];
            }
            v[4] = (short)0x3F80;   // bf16 1.0
        }
        ax[m] = v;
    }

    float* outF = (float*)out;
    u16*   outB = (u16*)out;

#pragma unroll 1
    for (int nt = 0; nt < 8; ++nt) {
        const f4 z4 = {0.f, 0.f, 0.f, 0.f};
        f4 aH[2], aR[2], aZ[2], aN[2], aI[2];
        bf8 biR = pWi[(nt     ) * 64 + l];
        bf8 biZ = pWi[(nt + 8 ) * 64 + l];
        bf8 biN = pWi[(nt + 16) * 64 + l];
#pragma unroll
        for (int m = 0; m < 2; ++m) {
            aH[m] = z4;
            aN[m] = z4;
            // swapped: weights as A-operand, x as B-operand -> D[n][batch]
            aR[m] = __builtin_amdgcn_mfma_f32_16x16x32_bf16(biR, ax[m], z4, 0, 0, 0);
            aZ[m] = __builtin_amdgcn_mfma_f32_16x16x32_bf16(biZ, ax[m], z4, 0, 0, 0);
            aI[m] = __builtin_amdgcn_mfma_f32_16x16x32_bf16(biN, ax[m], z4, 0, 0, 0);
        }
#pragma unroll
        for (int kb = 0; kb < 8; ++kb) {
            bf8 bH = pU[(nt * 8 + kb) * 64 + l];
            bf8 bR = pV[((nt     ) * 8 + kb) * 64 + l];   // V cols [0,128)   (hr)
            bf8 bZ = pV[((nt + 8 ) * 8 + kb) * 64 + l];   // V cols [128,256) (hz)
            bf8 bN = pV[((nt + 16) * 8 + kb) * 64 + l];   // V cols [256,384) (hn)
#pragma unroll
            for (int m = 0; m < 2; ++m) {
                aH[m] = __builtin_amdgcn_mfma_f32_16x16x32_bf16(bH, a[m][kb], aH[m], 0, 0, 0);
                aR[m] = __builtin_amdgcn_mfma_f32_16x16x32_bf16(bR, a[m][kb], aR[m], 0, 0, 0);
                aZ[m] = __builtin_amdgcn_mfma_f32_16x16x32_bf16(bZ, a[m][kb], aZ[m], 0, 0, 0);
                aN[m] = __builtin_amdgcn_mfma_f32_16x16x32_bf16(bN, a[m][kb], aN[m], 0, 0, 0);
            }
        }
        // C/D layout with swapped operands: col(lane&15) = batch, row(q*4+i) = n.
        // Lane's 4 regs = n = nt*16 + q*4 + {0..3} -> 16B contiguous in output row.
        int c0 = nt * 16 + q * 4;
        f4 bh4 = *(const f4*)(bhnF + c0);
#pragma unroll
        for (int m = 0; m < 2; ++m) {
            int row = g0 + m * 16 + lr;
            f4 o;
#pragma unroll
            for (int i = 0; i < 4; ++i) {
                float hv = aH[m][i];                              // h in fp32, no round trip
                float sr = fminf(fmaxf(aR[m][i], -30.f), 30.f);   // = ir + bi_r + hr
                float r  = __fdividef(1.f, 1.f + __expf(-sr));
                float sz = fminf(fmaxf(aZ[m][i], -30.f), 30.f);
                float z  = __fdividef(1.f, 1.f + __expf(-sz));
                float t  = aI[m][i] + r * (aN[m][i] + bh4[i]);    // i_n + bi_n + r*(hn + bhn)
                t = fminf(fmaxf(t, -15.f), 15.f);
                float e2t = __expf(2.f * t);
                float n = (e2t - 1.f) * __fdividef(1.f, e2t + 1.f);
                o[i] = (1.f - z) * n + z * hv;
            }
            int off = row * 128 + c0;
            if constexpr (FP32) {
                *(f4*)(outF + off) = o;                           // dwordx4, 16B aligned
                if (write2) *(f4*)(outF + NROWS * 128 + off) = o;
            } else {
                unsigned lo = (unsigned)f2bf(o[0]) | ((unsigned)f2bf(o[1]) << 16);
                unsigned hi = (unsigned)f2bf(o[2]) | ((unsigned)f2bf(o[3]) << 16);
                u64 pk = ((u64)hi << 32) | lo;
                *(u64*)(outB + off) = pk;                         // dwordx2, 8B aligned
                if (write2) *(u64*)(outB + NROWS * 128 + off) = pk;
            }
        }
    }
}

extern "C" void kernel_launch(void* const* d_in, const int* in_sizes, int n_in,
                              void* d_out, int out_size, void* d_ws, size_t ws_size,
                              hipStream_t stream) {
    const void* x    = d_in[0];
    const void* h1   = d_in[1];
    const void* h2   = d_in[2];
    const void* U1   = d_in[3];
    const void* U2   = d_in[4];
    const void* Wi   = d_in[5];
    const void* bi   = d_in[6];
    const void* Whrz = d_in[7];
    const void* Whn  = d_in[8];
    const void* bhn  = d_in[9];
    char* ws   = (char*)d_ws;
    int* flag  = (int*)(ws + FLAG_B);
    int write2 = (out_size >= 2 * NROWS * 128) ? 1 : 0;

    detect_mode<<<1, 64, 0, stream>>>((const u16*)h1, flag);
    const int pblk = (PACK_ITEMS + 255) / 256;
    prep_pack<false><<<pblk, 256, 0, stream>>>(U1, U2, Whrz, Whn, Wi, bi, bhn, ws, flag);
    prep_pack<true ><<<pblk, 256, 0, stream>>>(U1, U2, Whrz, Whn, Wi, bi, bhn, ws, flag);
    gru_fused<false><<<NROWS / 128, 256, 0, stream>>>(x, h1, h2, ws, d_out, flag, write2);
    gru_fused<true ><<<NROWS / 128, 256, 0, stream>>>(x, h1, h2, ws, d_out, flag, write2);
}